// Round 14
// baseline (74.030 us; speedup 1.0000x reference)
//
#include <hip/hip_runtime.h>
#include <hip/hip_bf16.h>
#include <stdint.h>

#define S_SCALE 30.0f
#define S_L2E_SC 0.33813165020835f  /* 30*log2(e)/128 : inputs scaled 8*16 */
#define N_ROWS 8192
#define D_DIM 256
#define C_CLS 10000
#define NCB 8

typedef __attribute__((ext_vector_type(16))) float f32x16;
typedef __attribute__((ext_vector_type(8))) int i32x8;

static __device__ __forceinline__ void gl16(const void* g, void* l) {
  __builtin_amdgcn_global_load_lds(
      (const __attribute__((address_space(1))) void*)g,
      (__attribute__((address_space(3))) void*)l, 16, 0, 0);
}

// 32-lane sum (within each 32-lane half), VALU DPP + one shfl_xor(16).
static __device__ __forceinline__ float row_sum32(float v) {
  union { float f; int i; } u, w;
  u.f = v;
  w.i = __builtin_amdgcn_update_dpp(0, u.i, 0xB1, 0xF, 0xF, true);  u.f += w.f; // lane^1
  w.i = __builtin_amdgcn_update_dpp(0, u.i, 0x4E, 0xF, 0xF, true);  u.f += w.f; // lane^2
  w.i = __builtin_amdgcn_update_dpp(0, u.i, 0x141, 0xF, 0xF, true); u.f += w.f; // half-mirror
  w.i = __builtin_amdgcn_update_dpp(0, u.i, 0x140, 0xF, 0xF, true); u.f += w.f; // row-mirror
  u.f += __shfl_xor(u.f, 16, 64);                                               // 16-row pair
  return u.f;
}

// ---- fused prep (fp8 e4m3, pre-scaled) into 32x32x64 MX-fragment layouts ----
// WbF8: [c32 0..319][kchunk 0..3][lane]32B; lane holds W[col=c32*32+(lane&31)]
// [k = kchunk*64 + (lane>>5)*32 .. +32]; cols >= C_CLS zero (exp2(0)=1,
// subtracted as a constant in k_loss1).
// xnb8: [panel 0..63][slot = r32*4+kchunk 0..15][lane]32B; lane holds
// xn[row = panel*128 + r32*32 + (lane&31)][k = kchunk*64 + (lane>>5)*32 .. +32].
__global__ __launch_bounds__(256) void k_prep(const float* __restrict__ x,
                                              const float* __restrict__ W,
                                              const int* __restrict__ target,
                                              unsigned char* __restrict__ xnb8,
                                              unsigned char* __restrict__ WbF8,
                                              float* __restrict__ tgt) {
  if (blockIdx.x < 1280) {
    int gidx = blockIdx.x * 256 + threadIdx.x;   // 0..327679 = 320*16*64
    int lane = gidx & 63;
    int kc = (gidx >> 6) & 15;
    int c32 = gidx >> 10;
    int col = c32 * 32 + (lane & 31);
    int k0 = kc * 16 + (lane >> 5) * 8;
    int r0 = 0, r1 = 0;
    if (col < C_CLS) {
      const float4 a = *(const float4*)(W + (size_t)col * D_DIM + k0);
      const float4 b = *(const float4*)(W + (size_t)col * D_DIM + k0 + 4);
      r0 = __builtin_amdgcn_cvt_pk_fp8_f32(a.x * 16.f, a.y * 16.f, 0, false);
      r0 = __builtin_amdgcn_cvt_pk_fp8_f32(a.z * 16.f, a.w * 16.f, r0, true);
      r1 = __builtin_amdgcn_cvt_pk_fp8_f32(b.x * 16.f, b.y * 16.f, 0, false);
      r1 = __builtin_amdgcn_cvt_pk_fp8_f32(b.z * 16.f, b.w * 16.f, r1, true);
    }
    int kchunk = k0 >> 6, lk = (k0 >> 5) & 1, j0 = k0 & 31;
    size_t dst = (size_t)c32 * 8192 + (size_t)kchunk * 2048 +
                 (size_t)((col & 31) + 32 * lk) * 32 + j0;
    *(int2*)(WbF8 + dst) = (int2){r0, r1};
  } else {
    int row = (blockIdx.x - 1280) * 4 + (threadIdx.x >> 6);
    int l = threadIdx.x & 63;
    const float4 v = *(const float4*)(x + (size_t)row * D_DIM + l * 4);
    float ss = v.x * v.x + v.y * v.y + v.z * v.z + v.w * v.w;
#pragma unroll
    for (int m = 1; m < 64; m <<= 1) ss += __shfl_xor(ss, m, 64);
    float rn = 1.0f / sqrtf(ss);
    float s8 = rn * 8.f;
    int r0 = __builtin_amdgcn_cvt_pk_fp8_f32(v.x * s8, v.y * s8, 0, false);
    r0 = __builtin_amdgcn_cvt_pk_fp8_f32(v.z * s8, v.w * s8, r0, true);
    // this thread's 4 k-values: k0 = l*4
    int panel = row >> 7, r32 = (row >> 5) & 3, lrow = row & 31;
    int kchunk = l >> 4, lk = (l >> 3) & 1, j0 = (l & 7) * 4;
    size_t dst = (size_t)panel * 32768 + (size_t)(r32 * 4 + kchunk) * 2048 +
                 (size_t)(lrow + 32 * lk) * 32 + j0;
    *(int*)(xnb8 + dst) = r0;
    // exact fp32 target logit
    int tc = target[row];
    const float4 b = *(const float4*)(W + (size_t)tc * D_DIM + l * 4);
    float s = v.x * b.x + v.y * b.y + v.z * b.z + v.w * b.w;
#pragma unroll
    for (int m = 1; m < 64; m <<= 1) s += __shfl_xor(s, m, 64);
    if (l == 0) tgt[row] = s * rn;
  }
}

// ------- barrier-free fused MX-fp8 GEMM (32x32x64, unity scales) + exp-sum ----
// 512 blocks (2/CU), 8 waves (2Mx4N), wave tile 64x64 = 2x2 frags of 32x32.
// K=256 = 4 kchunks of 64. Per kchunk: 2 B-frag loads (32B/lane = 2 dwordx4,
// L2) double-buffered + 2 A-frag ds reads (32B = 2 ds_read_b128) + 4 MFMA at
// 2x the non-scaled fp8 rate (4686 TF uBench). 32B/lane loads put 4x the bytes
// in flight per wave vs the 8B frags of rounds 11-13 (Little's-law fix for the
// ~700cyc/load equilibrium). Scales = E8M0 127 (1.0) -> numerics identical to
// non-scaled fp8. acc 64 AGPR + Bdbuf 32 + A 8 + addr ~ 120 -> 4 waves/SIMD.
__global__ __launch_bounds__(512, 4) void k_gemm(const unsigned char* __restrict__ xnb8,
                                                 const unsigned char* __restrict__ WbF8,
                                                 float* __restrict__ partials) {
  __shared__ __align__(16) char lds[34816];   // A frags 32 KB @0; rsum 2 KB @32768
  const int b = blockIdx.x;
  const int cg = b & 7;                              // XCD colgroup 0..7
  const int br = b >> 3;                             // row panel 0..63 (128 rows)
  const int bc0 = cg * 5;                            // 5 consecutive 256-col tiles
  const int t = threadIdx.x;
  const int w = t >> 6, l = t & 63;
  const int wr = w >> 2, wc = w & 3;                 // 2M x 4N waves (64x64 tile)
  float* rsumAll = (float*)(lds + 32768);            // [8 waves][64 rows]

  if (t < 512) rsumAll[t] = 0.f;                     // covered by staging barrier

  // ---- stage A panel once: pure linear 32 KB copy into frag-order LDS ----
  {
    const char* Ag = (const char*)xnb8 + (size_t)br * 32768;
#pragma unroll
    for (int i = 0; i < 4; ++i)
      gl16(Ag + i * 8192 + w * 1024 + l * 16, lds + i * 8192 + w * 1024);
    asm volatile("s_waitcnt vmcnt(0)" ::: "memory");
    __builtin_amdgcn_sched_barrier(0);
    __builtin_amdgcn_s_barrier();
  }

  f32x16 acc[2][2];
#pragma unroll
  for (int m = 0; m < 2; m++)
#pragma unroll
    for (int n = 0; n < 2; n++)
#pragma unroll
      for (int j = 0; j < 16; j++) acc[m][n][j] = 0.f;

  // wave's A base in LDS: frag (fm,kc) at + (fm*4+kc)*2048, per-lane 32B
  const char* AwL = lds + (size_t)wr * 16384 + (size_t)l * 32;
  // wave's B bases in global frag layout (c32 = bc0*8 + wc*2 + fn), per-lane 32B
  const unsigned char* Bw0 = WbF8 + (size_t)(bc0 * 8 + wc * 2) * 8192 + (size_t)l * 32;
  const unsigned char* Bw1 = Bw0 + 8192;
  float* rw = rsumAll + w * 64;                      // this wave's private rows

  i32x8 b0[2], b1[2];
  b0[0] = *(const i32x8*)Bw0;
  b0[1] = *(const i32x8*)Bw1;

  for (int tt = 0; tt < 5; ++tt) {
    auto step = [&](int kc, i32x8(&cur)[2], i32x8(&nxt)[2]) {
      if (kc < 3) {
        nxt[0] = *(const i32x8*)(Bw0 + (kc + 1) * 2048);
        nxt[1] = *(const i32x8*)(Bw1 + (kc + 1) * 2048);
      } else if (tt < 4) {
        // prefetch next tile's kchunk 0 under this tile's epilogue VALU
        nxt[0] = *(const i32x8*)(Bw0 + 65536);
        nxt[1] = *(const i32x8*)(Bw1 + 65536);
      }
      __builtin_amdgcn_s_setprio(1);
#pragma unroll
      for (int fm = 0; fm < 2; ++fm) {
        i32x8 a = *(const i32x8*)(AwL + (fm * 4 + kc) * 2048);
        acc[fm][0] = __builtin_amdgcn_mfma_scale_f32_32x32x64_f8f6f4(
            a, cur[0], acc[fm][0], 0, 0, 0, 127, 0, 127);
        acc[fm][1] = __builtin_amdgcn_mfma_scale_f32_32x32x64_f8f6f4(
            a, cur[1], acc[fm][1], 0, 0, 0, 127, 0, 127);
      }
      __builtin_amdgcn_s_setprio(0);
    };
    step(0, b0, b1); step(1, b1, b0); step(2, b0, b1); step(3, b1, b0);
    // after step3: b0 holds next tile's kchunk-0 frags (loads in flight)

    // ---- per-tile epilogue: exp2, 32-lane col-reduce, accumulate LDS rows ----
    // 32x32 C/D: col = lane&31, row = (reg&3) + 8*(reg>>2) + 4*(lane>>5).
#pragma unroll
    for (int fm = 0; fm < 2; ++fm) {
#pragma unroll
      for (int j = 0; j < 16; ++j) {
        float rs = __builtin_amdgcn_exp2f(acc[fm][0][j] * S_L2E_SC) +
                   __builtin_amdgcn_exp2f(acc[fm][1][j] * S_L2E_SC);
        rs = row_sum32(rs);
        if ((l & 31) == 0) {
          int row = fm * 32 + (j & 3) + 8 * (j >> 2) + 4 * (l >> 5);
          rw[row] += rs;
        }
        acc[fm][0][j] = 0.f;
        acc[fm][1][j] = 0.f;
      }
    }
    Bw0 += 65536;   // next bc tile (8 c32-blks * 4 kchunk * 2048 B)
    Bw1 += 65536;
  }

  // ---- final: combine 4 wc-waves per row, one coalesced store ----
  __syncthreads();
  if (t < 128) {
    int wr2 = t >> 6, r = t & 63;
    float sv = rsumAll[(wr2 * 4 + 0) * 64 + r] + rsumAll[(wr2 * 4 + 1) * 64 + r] +
               rsumAll[(wr2 * 4 + 2) * 64 + r] + rsumAll[(wr2 * 4 + 3) * 64 + r];
    partials[(size_t)cg * N_ROWS + (size_t)br * 128 + t] = sv;
  }
}

// ---------------- per-row loss + block partial sums ----------------
__global__ __launch_bounds__(256) void k_loss1(const float* __restrict__ partials,
                                               const float* __restrict__ tgt,
                                               float* __restrict__ bsum) {
  __shared__ float wsum[4];
  int i = blockIdx.x * 256 + threadIdx.x;
  const float* p = partials + i;
  float s = -240.0f;   // remove padded cols 10000..10239 (W=0 -> exp term 1.0)
#pragma unroll
  for (int j = 0; j < NCB; ++j) s += p[(size_t)j * N_ROWS];
  float tl = tgt[i];
  float tcv = fminf(fmaxf(tl, -1.0f + 1e-7f), 1.0f - 1e-7f);
  const float cm = 0.95533648912560601964f;   // cos(0.3)
  const float sm = 0.29552020666133957510f;   // sin(0.3)
  float num = S_SCALE * (tcv * cm - sqrtf(fmaxf(1.0f - tcv * tcv, 0.f)) * sm);
  float sum_excl = s - __expf(S_SCALE * tl);
  float denom = __expf(num) + sum_excl;
  float L = num - __logf(denom);
#pragma unroll
  for (int m = 1; m < 64; m <<= 1) L += __shfl_xor(L, m, 64);
  int l = threadIdx.x & 63, w = threadIdx.x >> 6;
  if (l == 0) wsum[w] = L;
  __syncthreads();
  if (threadIdx.x == 0) bsum[blockIdx.x] = wsum[0] + wsum[1] + wsum[2] + wsum[3];
}

__global__ void k_loss2(const float* __restrict__ bsum, float* __restrict__ out) {
  float s = 0.f;
  for (int i = 0; i < 32; ++i) s += bsum[i];
  out[0] = -s / (float)N_ROWS;
}

// ---------------- launch ----------------
extern "C" void kernel_launch(void* const* d_in, const int* in_sizes, int n_in,
                              void* d_out, int out_size, void* d_ws, size_t ws_size,
                              hipStream_t stream) {
  const float* x = (const float*)d_in[0];
  const float* W = (const float*)d_in[1];
  const int* target = (const int*)d_in[2];
  float* out = (float*)d_out;
  char* ws = (char*)d_ws;

  unsigned char* xnb8 = (unsigned char*)(ws);               // 64*32768     = 2,097,152
  unsigned char* WbF8 = (unsigned char*)(ws + 2097152);     // 320*8192     = 2,621,440
  float* tgt = (float*)(ws + 4718592);                      // 8192*4
  float* partials = (float*)(ws + 4751360);                 // 8*8192*4     = 262,144
  float* bsum = (float*)(ws + 5013504);                     // 32*4

  k_prep<<<3328, 256, 0, stream>>>(x, W, target, xnb8, WbF8, tgt);
  k_gemm<<<512, 512, 0, stream>>>(xnb8, WbF8, partials);
  k_loss1<<<32, 256, 0, stream>>>(partials, tgt, bsum);
  k_loss2<<<1, 1, 0, stream>>>(bsum, out);
}

// Round 15
// 62.887 us; speedup vs baseline: 1.1772x; 1.1772x over previous
//
#include <hip/hip_runtime.h>
#include <hip/hip_bf16.h>
#include <stdint.h>

#define S_SCALE 30.0f
#define S_L2E_SC 0.33813165020835f  /* 30*log2(e)/128 : inputs scaled 8*16 */
#define N_ROWS 8192
#define D_DIM 256
#define C_CLS 10000
#define NCB 16

typedef __attribute__((ext_vector_type(16))) float f32x16;
typedef __attribute__((ext_vector_type(8))) int i32x8;

static __device__ __forceinline__ void gl16(const void* g, void* l) {
  __builtin_amdgcn_global_load_lds(
      (const __attribute__((address_space(1))) void*)g,
      (__attribute__((address_space(3))) void*)l, 16, 0, 0);
}

// load one 32B/lane MX fragment stored half-split (two 16B-dense 1KB regions)
static __device__ __forceinline__ i32x8 ld32(const char* p) {
  union { i32x8 v; struct { int4 a, b; } s; } u;
  u.s.a = *(const int4*)p;
  u.s.b = *(const int4*)(p + 1024);
  return u.v;
}

// 32-lane sum (within each 32-lane half), VALU DPP + one shfl_xor(16).
static __device__ __forceinline__ float row_sum32(float v) {
  union { float f; int i; } u, w;
  u.f = v;
  w.i = __builtin_amdgcn_update_dpp(0, u.i, 0xB1, 0xF, 0xF, true);  u.f += w.f; // lane^1
  w.i = __builtin_amdgcn_update_dpp(0, u.i, 0x4E, 0xF, 0xF, true);  u.f += w.f; // lane^2
  w.i = __builtin_amdgcn_update_dpp(0, u.i, 0x141, 0xF, 0xF, true); u.f += w.f; // half-mirror
  w.i = __builtin_amdgcn_update_dpp(0, u.i, 0x140, 0xF, 0xF, true); u.f += w.f; // row-mirror
  u.f += __shfl_xor(u.f, 16, 64);                                               // 16-row pair
  return u.f;
}

// ---- fused prep (fp8 e4m3, pre-scaled) into HALF-SPLIT 32x32x64 MX layouts ----
// Fragment (c32|r32, kchunk): 2048 B = half0 (bytes 0-15 of each lane, 16B-dense
// at fl*16) + half1 (bytes 16-31 at 1024 + fl*16); fl = (col_or_row & 31) +
// 32*k32sec. WbF8: [c32 0..319][kchunk 0..3] frags; cols >= C_CLS zero
// (exp2(0)=1, subtracted in k_loss1). xnb8: [panel 0..63][r32*4+kchunk] frags.
__global__ __launch_bounds__(256) void k_prep(const float* __restrict__ x,
                                              const float* __restrict__ W,
                                              const int* __restrict__ target,
                                              unsigned char* __restrict__ xnb8,
                                              unsigned char* __restrict__ WbF8,
                                              float* __restrict__ tgt) {
  if (blockIdx.x < 1280) {
    int gidx = blockIdx.x * 256 + threadIdx.x;   // 0..327679 = 320*16*64
    int lane = gidx & 63;
    int kc = (gidx >> 6) & 15;
    int c32 = gidx >> 10;
    int hi = lane >> 5;
    int col = c32 * 32 + (lane & 31);
    int k0 = kc * 16 + hi * 8;
    int r0 = 0, r1 = 0;
    if (col < C_CLS) {
      const float4 a = *(const float4*)(W + (size_t)col * D_DIM + k0);
      const float4 b = *(const float4*)(W + (size_t)col * D_DIM + k0 + 4);
      r0 = __builtin_amdgcn_cvt_pk_fp8_f32(a.x * 16.f, a.y * 16.f, 0, false);
      r0 = __builtin_amdgcn_cvt_pk_fp8_f32(a.z * 16.f, a.w * 16.f, r0, true);
      r1 = __builtin_amdgcn_cvt_pk_fp8_f32(b.x * 16.f, b.y * 16.f, 0, false);
      r1 = __builtin_amdgcn_cvt_pk_fp8_f32(b.z * 16.f, b.w * 16.f, r1, true);
    }
    int kchunk = kc >> 2;
    int lk = (kc >> 1) & 1;               // which 32-k section
    int half = kc & 1;                    // which 16B half of the lane's 32B
    int fl = (col & 31) + 32 * lk;
    size_t dst = (size_t)c32 * 8192 + (size_t)kchunk * 2048 +
                 (size_t)half * 1024 + (size_t)fl * 16 + hi * 8;
    *(int2*)(WbF8 + dst) = (int2){r0, r1};
  } else {
    int row = (blockIdx.x - 1280) * 4 + (threadIdx.x >> 6);
    int l = threadIdx.x & 63;
    const float4 v = *(const float4*)(x + (size_t)row * D_DIM + l * 4);
    float ss = v.x * v.x + v.y * v.y + v.z * v.z + v.w * v.w;
#pragma unroll
    for (int m = 1; m < 64; m <<= 1) ss += __shfl_xor(ss, m, 64);
    float rn = 1.0f / sqrtf(ss);
    float s8 = rn * 8.f;
    int r0 = __builtin_amdgcn_cvt_pk_fp8_f32(v.x * s8, v.y * s8, 0, false);
    r0 = __builtin_amdgcn_cvt_pk_fp8_f32(v.z * s8, v.w * s8, r0, true);
    // this thread's 4 k-bytes: k0 = l*4
    int panel = row >> 7, r32 = (row >> 5) & 3;
    int kchunk = l >> 4;
    int lk = (l >> 3) & 1;
    int j = (l & 7) * 4;
    int half = (l >> 2) & 1;
    int fl = (row & 31) + 32 * lk;
    size_t dst = (size_t)panel * 32768 + (size_t)(r32 * 4 + kchunk) * 2048 +
                 (size_t)half * 1024 + (size_t)fl * 16 + (j & 15);
    *(int*)(xnb8 + dst) = r0;
    // exact fp32 target logit
    int tc = target[row];
    const float4 b = *(const float4*)(W + (size_t)tc * D_DIM + l * 4);
    float s = v.x * b.x + v.y * b.y + v.z * b.z + v.w * b.w;
#pragma unroll
    for (int m = 1; m < 64; m <<= 1) s += __shfl_xor(s, m, 64);
    if (l == 0) tgt[row] = s * rn;
  }
}

// ------- barrier-free fused MX-fp8 GEMM (32x32x64, unity scales) + exp-sum ----
// 1024 blocks (64 br x 8 cg x 2 sub), 256 thr (4 waves, 2wr x 2wc), wave tile
// 64x64, block tile 128x128, 5 tiles/block. 3 blocks/CU (launch_bounds(256,3),
// ~156 regs < 168 cap -> no spill; r14's (512,4)=128 cap spilled 146 MB).
// Prefetch granularity = KCHUNK-PAIR (8 MFMA ~ 136 cyc own-work per window;
// x3 interleaved waves ~ 400+ cyc wall >= L2 latency) -- fixes the depth-1
// ~40% equilibrium of r11-r14. Buffer parity == tile-half -> static reg names.
// All frag reads 16B-dense (half-split layout): LDS conflict-free, global
// coalesced. Scales = E8M0 127 (1.0): numerics == non-scaled fp8.
__global__ __launch_bounds__(256, 3) void k_gemm(const unsigned char* __restrict__ xnb8,
                                                 const unsigned char* __restrict__ WbF8,
                                                 float* __restrict__ partials) {
  __shared__ __align__(16) char lds[33792];   // A frags 32 KB @0; rsum 1 KB @32768
  const int b = blockIdx.x;
  const int cg = b & 7;                        // XCD colgroup (1280 cols)
  const int q = b >> 3;
  const int br = q & 63;                       // row panel (128 rows)
  const int sub = q >> 6;                      // col sub-half (640 cols)
  const int t = threadIdx.x;
  const int w = t >> 6, l = t & 63;
  const int wr = w >> 1, wc = w & 1;           // 2M x 2N waves (64x64 tile)
  float* rsumAll = (float*)(lds + 32768);      // [4 waves][64 rows]

  rsumAll[t] = 0.f;                            // covered by staging barrier

  // ---- stage A panel once: linear 32 KB copy into half-split frag LDS ----
  {
    const char* Ag = (const char*)xnb8 + (size_t)br * 32768;
#pragma unroll
    for (int i = 0; i < 8; ++i)
      gl16(Ag + i * 4096 + w * 1024 + l * 16, lds + i * 4096 + w * 1024);
    asm volatile("s_waitcnt vmcnt(0)" ::: "memory");
    __builtin_amdgcn_sched_barrier(0);
    __builtin_amdgcn_s_barrier();
  }

  f32x16 acc[2][2];
#pragma unroll
  for (int m = 0; m < 2; m++)
#pragma unroll
    for (int n = 0; n < 2; n++)
#pragma unroll
      for (int j = 0; j < 16; j++) acc[m][n][j] = 0.f;

  // A frag (fmg, kc) at lds + (fmg*4+kc)*2048 (+half*1024 inside ld32)
  const char* AwL = lds + (size_t)l * 16;
  // B base: c32 = cg*40 + sub*20 + tt*4 + wc*2 + fn
  const char* Bwv = (const char*)WbF8 +
                    (size_t)(cg * 40 + sub * 20 + wc * 2) * 8192 + (size_t)l * 16;
  float* rw = rsumAll + w * 64;                // this wave's private rows

  // B half-buffers: P (kchunks 0,1), Q (kchunks 2,3) -- static names
  i32x8 p00, p01, p10, p11, q00, q01, q10, q11;
  p00 = ld32(Bwv);            p01 = ld32(Bwv + 8192);
  p10 = ld32(Bwv + 2048);     p11 = ld32(Bwv + 8192 + 2048);

  auto comp = [&](int kc, const i32x8& bf0, const i32x8& bf1) {
    __builtin_amdgcn_s_setprio(1);
#pragma unroll
    for (int fm = 0; fm < 2; ++fm) {
      i32x8 a = ld32(AwL + ((wr * 2 + fm) * 4 + kc) * 2048);
      acc[fm][0] = __builtin_amdgcn_mfma_scale_f32_32x32x64_f8f6f4(
          a, bf0, acc[fm][0], 0, 0, 0, 127, 0, 127);
      acc[fm][1] = __builtin_amdgcn_mfma_scale_f32_32x32x64_f8f6f4(
          a, bf1, acc[fm][1], 0, 0, 0, 127, 0, 127);
    }
    __builtin_amdgcn_s_setprio(0);
  };

  for (int tt = 0; tt < 5; ++tt) {
    const char* Bt = Bwv + (size_t)tt * 32768;
    // issue Q <- (tt, kchunks 2,3) while computing with P
    q00 = ld32(Bt + 2 * 2048);        q01 = ld32(Bt + 8192 + 2 * 2048);
    q10 = ld32(Bt + 3 * 2048);        q11 = ld32(Bt + 8192 + 3 * 2048);
    comp(0, p00, p01);
    comp(1, p10, p11);
    // issue P <- (tt+1, kchunks 0,1) while computing with Q (+ epilogue)
    if (tt < 4) {
      p00 = ld32(Bt + 32768);         p01 = ld32(Bt + 32768 + 8192);
      p10 = ld32(Bt + 32768 + 2048);  p11 = ld32(Bt + 32768 + 8192 + 2048);
    }
    comp(2, q00, q01);
    comp(3, q10, q11);

    // ---- per-tile epilogue: exp2, 32-lane col-reduce, accumulate LDS rows ----
    // 32x32 C/D: col = lane&31, row = (reg&3) + 8*(reg>>2) + 4*(lane>>5).
#pragma unroll
    for (int fm = 0; fm < 2; ++fm) {
#pragma unroll
      for (int j = 0; j < 16; ++j) {
        float rs = __builtin_amdgcn_exp2f(acc[fm][0][j] * S_L2E_SC) +
                   __builtin_amdgcn_exp2f(acc[fm][1][j] * S_L2E_SC);
        rs = row_sum32(rs);
        if ((l & 31) == 0) {
          int row = fm * 32 + (j & 3) + 8 * (j >> 2) + 4 * (l >> 5);
          rw[row] += rs;
        }
        acc[fm][0][j] = 0.f;
        acc[fm][1][j] = 0.f;
      }
    }
  }

  // ---- final: combine 2 wc-waves per row, one coalesced store ----
  __syncthreads();
  if (t < 128) {
    int wr2 = t >> 6, r = t & 63;
    float sv = rsumAll[(wr2 * 2 + 0) * 64 + r] + rsumAll[(wr2 * 2 + 1) * 64 + r];
    partials[(size_t)(cg * 2 + sub) * N_ROWS + (size_t)br * 128 + t] = sv;
  }
}

// ---------------- per-row loss + block partial sums ----------------
__global__ __launch_bounds__(256) void k_loss1(const float* __restrict__ partials,
                                               const float* __restrict__ tgt,
                                               float* __restrict__ bsum) {
  __shared__ float wsum[4];
  int i = blockIdx.x * 256 + threadIdx.x;
  const float* p = partials + i;
  float s = -240.0f;   // remove padded cols 10000..10239 (W=0 -> exp term 1.0)
#pragma unroll
  for (int j = 0; j < NCB; ++j) s += p[(size_t)j * N_ROWS];
  float tl = tgt[i];
  float tcv = fminf(fmaxf(tl, -1.0f + 1e-7f), 1.0f - 1e-7f);
  const float cm = 0.95533648912560601964f;   // cos(0.3)
  const float sm = 0.29552020666133957510f;   // sin(0.3)
  float num = S_SCALE * (tcv * cm - sqrtf(fmaxf(1.0f - tcv * tcv, 0.f)) * sm);
  float sum_excl = s - __expf(S_SCALE * tl);
  float denom = __expf(num) + sum_excl;
  float L = num - __logf(denom);
#pragma unroll
  for (int m = 1; m < 64; m <<= 1) L += __shfl_xor(L, m, 64);
  int l = threadIdx.x & 63, w = threadIdx.x >> 6;
  if (l == 0) wsum[w] = L;
  __syncthreads();
  if (threadIdx.x == 0) bsum[blockIdx.x] = wsum[0] + wsum[1] + wsum[2] + wsum[3];
}

__global__ void k_loss2(const float* __restrict__ bsum, float* __restrict__ out) {
  float s = 0.f;
  for (int i = 0; i < 32; ++i) s += bsum[i];
  out[0] = -s / (float)N_ROWS;
}

// ---------------- launch ----------------
extern "C" void kernel_launch(void* const* d_in, const int* in_sizes, int n_in,
                              void* d_out, int out_size, void* d_ws, size_t ws_size,
                              hipStream_t stream) {
  const float* x = (const float*)d_in[0];
  const float* W = (const float*)d_in[1];
  const int* target = (const int*)d_in[2];
  float* out = (float*)d_out;
  char* ws = (char*)d_ws;

  unsigned char* xnb8 = (unsigned char*)(ws);               // 64*32768     = 2,097,152
  unsigned char* WbF8 = (unsigned char*)(ws + 2097152);     // 320*8192     = 2,621,440
  float* tgt = (float*)(ws + 4718592);                      // 8192*4
  float* partials = (float*)(ws + 4751360);                 // 16*8192*4    = 524,288
  float* bsum = (float*)(ws + 5275648);                     // 32*4

  k_prep<<<3328, 256, 0, stream>>>(x, W, target, xnb8, WbF8, tgt);
  k_gemm<<<1024, 256, 0, stream>>>(xnb8, WbF8, partials);
  k_loss1<<<32, 256, 0, stream>>>(partials, tgt, bsum);
  k_loss2<<<1, 1, 0, stream>>>(bsum, out);
}